// Round 4
// baseline (451.491 us; speedup 1.0000x reference)
//
#include <hip/hip_runtime.h>
#include <math.h>
#include <type_traits>

typedef float f4 __attribute__((ext_vector_type(4)));

#define DD 160
#define HH 160
#define WW 160
#define BB 4
#define KK 11
#define RAD 5
#define TH 16
#define TW 16
#define DCH 32
#define NPLANES (DCH + 2 * RAD)   // 42 (loop padded to 44 = 4*11)
#define NDCH (DD / DCH)           // 5
#define HALO_H (TH + 2 * RAD)     // 26
#define TS 16                     // tmp row stride (phase-2 scalar reads: 2-way = free)
#define STAT (HALO_H * TS)        // 416 floats per stat plane

struct GaussW { float g[KK]; };

// 256 threads (4 waves). Register-prefetch dataflow (proven R0/R1), scalar D-ring
// (55 regs), weights read from kernarg SGPRs (saves 11 VGPRs), per-plane barrier is
// raw lgkmcnt(0)+s_barrier (no vmcnt(0) drain -> prefetch latency spans full plane).
// launch_bounds (256,2): ArchVGPR cap 128 (R1/R2 showed (256,4) caps at 64 -> spill).
__global__ __launch_bounds__(256, 2)
void ssim3d_kernel(const float* __restrict__ img1,
                   const float* __restrict__ img2,
                   float* __restrict__ out, GaussW gw)
{
    __shared__ __align__(16) float tmpA[5 * STAT];   // W-conv result dbuf
    __shared__ __align__(16) float tmpB[5 * STAT];
    __shared__ float wsum[4];

    const int tid = threadIdx.x;        // 256 threads = 4 waves
    // phase-2 mapping: 16 rows x 16 cols, one scalar col per thread
    const int xc = tid & 15;
    const int ty = tid >> 4;
    // phase-1 mapping: 26 rows x 4 quads (threads 0..103 active)
    const int p1r = tid >> 2;
    const int p1q = tid & 3;

    const int blk = blockIdx.x;
    const int bw = blk % 10;
    const int bh = (blk / 10) % 10;
    const int bd = (blk / 100) % NDCH;
    const int bb = blk / (100 * NDCH);

    const int oh0 = bh * TH, ow0 = bw * TW, od0 = bd * DCH;
    const float* base1 = img1 + (size_t)bb * DD * HH * WW;
    const float* base2 = img2 + (size_t)bb * DD * HH * WW;

    // static D-ring: slot s holds output q with q % 11 == s (scalar, 1 col/thread)
    float a1[KK], a2[KK], a11[KK], a22[KK], a12[KK];
#pragma unroll
    for (int i = 0; i < KK; ++i) { a1[i]=0.f; a2[i]=0.f; a11[i]=0.f; a22[i]=0.f; a12[i]=0.f; }

    float lsum = 0.f;

    // phase-1 per-thread constants
    const int gh = oh0 - RAD + p1r;
    const bool p1act = (p1r < HALO_H);
    const bool rowok = p1act && ((unsigned)gh < (unsigned)HH);
    const int gc0 = ow0 + 4 * p1q - 8;                    // first loaded col (16B aligned)
    const size_t rowoff = (size_t)((unsigned)gh < (unsigned)HH ? gh : 0) * WW;

    // prefetch registers for the next plane's 20 cols per thread
    f4 pa[5], pb[5];
#pragma unroll
    for (int j = 0; j < 5; ++j) { pa[j] = (f4)0.f; pb[j] = (f4)0.f; }

    float* twr = tmpA;   // buffer written (and read) this plane
    float* trd = tmpB;   // previous plane's buffer

    // preamble: prefetch plane p=0 if valid
    {
        const int dn = od0 - RAD;
        if (p1act && (unsigned)dn < (unsigned)DD) {
            const size_t pbv = (size_t)dn * (HH * WW) + rowoff;
#pragma unroll
            for (int j = 0; j < 5; ++j) {
                const int gc = gc0 + 4 * j;
                f4 za = (f4)0.f, zb = (f4)0.f;
                if (rowok && gc >= 0 && gc <= WW - 4) {
                    za = *(const f4*)(base1 + pbv + gc);
                    zb = *(const f4*)(base2 + pbv + gc);
                }
                pa[j] = za; pb[j] = zb;
            }
        }
    }

    int pcbase = 0;
    auto body = [&](auto uc) {
        constexpr int U = decltype(uc)::value;
        const int p = pcbase + U;
        const int d = od0 - RAD + p;
        const bool dval = (p < NPLANES) && ((unsigned)d < (unsigned)DD);  // block-uniform

        // ---- phase 1: W-conv of 5 stats from prefetched regs (threads 0..103) ----
        if (dval && p1act) {
            float t1[4]  = {0.f,0.f,0.f,0.f};
            float t2[4]  = {0.f,0.f,0.f,0.f};
            float t11[4] = {0.f,0.f,0.f,0.f};
            float t22[4] = {0.f,0.f,0.f,0.f};
            float t12[4] = {0.f,0.f,0.f,0.f};
#pragma unroll
            for (int j = 0; j < 5; ++j) {
#pragma unroll
                for (int ii = 0; ii < 4; ++ii) {
                    const int i = 4 * j + ii;          // window col 0..19; need 3..16
                    if (i < 3 || i > 16) continue;
                    const float av = pa[j][ii], bv = pb[j][ii];
                    const float aa = av * av, bb2 = bv * bv, ab = av * bv;
#pragma unroll
                    for (int m = 0; m < 4; ++m) {
                        const int k = i - m - 3;       // tap index (compile-time)
                        if (k >= 0 && k < KK) {
                            const float w = gw.g[k];   // SGPR (kernarg)
                            t1[m]  += w * av;
                            t2[m]  += w * bv;
                            t11[m] += w * aa;
                            t22[m] += w * bb2;
                            t12[m] += w * ab;
                        }
                    }
                }
            }
            float* tw = twr + p1r * TS + 4 * p1q;      // 16B-aligned
            f4 v;
            v[0]=t1[0];  v[1]=t1[1];  v[2]=t1[2];  v[3]=t1[3];  *(f4*)(tw + 0*STAT) = v;
            v[0]=t2[0];  v[1]=t2[1];  v[2]=t2[2];  v[3]=t2[3];  *(f4*)(tw + 1*STAT) = v;
            v[0]=t11[0]; v[1]=t11[1]; v[2]=t11[2]; v[3]=t11[3]; *(f4*)(tw + 2*STAT) = v;
            v[0]=t22[0]; v[1]=t22[1]; v[2]=t22[2]; v[3]=t22[3]; *(f4*)(tw + 3*STAT) = v;
            v[0]=t12[0]; v[1]=t12[1]; v[2]=t12[2]; v[3]=t12[3]; *(f4*)(tw + 4*STAT) = v;
        }

        // ---- prefetch plane p+1 into pa/pb (consumed next body; waitcnt at use) ----
        {
            const int pn = p + 1;
            const int dn = od0 - RAD + pn;
            if (p1act && (pn < NPLANES) && ((unsigned)dn < (unsigned)DD)) {
                const size_t pbv = (size_t)dn * (HH * WW) + rowoff;
#pragma unroll
                for (int j = 0; j < 5; ++j) {
                    const int gc = gc0 + 4 * j;
                    f4 za = (f4)0.f, zb = (f4)0.f;
                    if (rowok && gc >= 0 && gc <= WW - 4) {
                        za = *(const f4*)(base1 + pbv + gc);
                        zb = *(const f4*)(base2 + pbv + gc);
                    }
                    pa[j] = za; pb[j] = zb;
                }
            }
        }

        // ---- phase 2: H-conv (scalar) + static-slot D scatter ----
        if (dval) {
            // Raw barrier: order LDS tmp traffic only (lgkmcnt). Deliberately NO
            // vmcnt(0) -- prefetch loads are thread-private register loads; the
            // compiler inserts their waitcnt at first use (next plane's phase 1).
            asm volatile("s_waitcnt lgkmcnt(0)\n\ts_barrier" ::: "memory");
            float P1 = 0.f, P2 = 0.f, P11 = 0.f, P22 = 0.f, P12 = 0.f;
            const float* tb = twr + (ty * TS + xc);
#pragma unroll
            for (int k = 0; k < KK; ++k) {
                const float w = gw.g[k];
                const int o = k * TS;
                P1  += w * tb[0*STAT + o];
                P2  += w * tb[1*STAT + o];
                P11 += w * tb[2*STAT + o];
                P22 += w * tb[3*STAT + o];
                P12 += w * tb[4*STAT + o];
            }
#pragma unroll
            for (int t = 0; t < KK; ++t) {
                constexpr int base = U + 22;
                const int s = (base - t) % 11;         // compile-time fold
                const float w = gw.g[t];
                a1[s]  += w * P1;
                a2[s]  += w * P2;
                a11[s] += w * P11;
                a22[s] += w * P22;
                a12[s] += w * P12;
            }
        }

        // ---- emit output q = p-10 from fixed slot (U+1)%11, then zero it ----
        constexpr int e = (U + 1) % 11;
        if (p >= 2 * RAD && p < NPLANES) {
            float mu1 = a1[e], mu2 = a2[e];
            float m11 = mu1 * mu1, m22 = mu2 * mu2, m12 = mu1 * mu2;
            float sg1 = a11[e] - m11, sg2 = a22[e] - m22, sg12 = a12[e] - m12;
            const float C1c = 0.0001f, C2c = 0.0009f;
            float num = (2.f * m12 + C1c) * (2.f * sg12 + C2c);
            float den = (m11 + m22 + C1c) * (sg1 + sg2 + C2c);
            lsum += num / den;
        }
        a1[e] = 0.f; a2[e] = 0.f; a11[e] = 0.f; a22[e] = 0.f; a12[e] = 0.f;

        // swap tmp double buffers
        float* t = twr; twr = trd; trd = t;
    };

    for (pcbase = 0; pcbase < 44; pcbase += 11) {
        body(std::integral_constant<int, 0>{});
        body(std::integral_constant<int, 1>{});
        body(std::integral_constant<int, 2>{});
        body(std::integral_constant<int, 3>{});
        body(std::integral_constant<int, 4>{});
        body(std::integral_constant<int, 5>{});
        body(std::integral_constant<int, 6>{});
        body(std::integral_constant<int, 7>{});
        body(std::integral_constant<int, 8>{});
        body(std::integral_constant<int, 9>{});
        body(std::integral_constant<int, 10>{});
    }

    // ---- reduction: wave shuffle -> LDS -> one atomic per block ----
    float v = lsum;
#pragma unroll
    for (int off = 32; off > 0; off >>= 1)
        v += __shfl_down(v, off, 64);
    if ((tid & 63) == 0) wsum[tid >> 6] = v;
    __syncthreads();
    if (tid == 0) {
        const float inv_n = 1.0f / ((float)BB * DD * HH * WW);
        atomicAdd(out, (wsum[0] + wsum[1] + wsum[2] + wsum[3]) * inv_n);
    }
}

extern "C" void kernel_launch(void* const* d_in, const int* in_sizes, int n_in,
                              void* d_out, int out_size, void* d_ws, size_t ws_size,
                              hipStream_t stream) {
    const float* img1 = (const float*)d_in[0];
    const float* img2 = (const float*)d_in[1];
    float* out = (float*)d_out;

    GaussW gw;
    double gd[KK], sum = 0.0;
    for (int i = 0; i < KK; ++i) {
        double x = (double)(i - KK / 2);
        gd[i] = exp(-(x * x) / (2.0 * 1.5 * 1.5));
        sum += gd[i];
    }
    for (int i = 0; i < KK; ++i) gw.g[i] = (float)(gd[i] / sum);

    hipMemsetAsync(d_out, 0, sizeof(float), stream);

    dim3 grid(10 * 10 * NDCH * BB);   // 2000 blocks
    dim3 block(256);                  // 4 waves
    hipLaunchKernelGGL(ssim3d_kernel, grid, block, 0, stream,
                       img1, img2, out, gw);
}

// Round 5
// 336.256 us; speedup vs baseline: 1.3427x; 1.3427x over previous
//
#include <hip/hip_runtime.h>
#include <math.h>
#include <type_traits>

typedef float f2 __attribute__((ext_vector_type(2)));
typedef float f4 __attribute__((ext_vector_type(4)));

#define DD 160
#define HH 160
#define WW 160
#define BB 4
#define KK 11
#define RAD 5
#define TH 16
#define TW 16
#define DCH 32
#define NPLANES (DCH + 2 * RAD)   // 42 (loop padded to 44 = 4*11)
#define NDCH (DD / DCH)           // 5
#define HALO_H (TH + 2 * RAD)     // 26
#define TS 16                     // tmp row stride: uniform banks (0 conflicts)
#define STAT (HALO_H * TS)        // 416 floats per stat plane

// Weight-pair table in kernarg: gg[2x] = G(x-2), gg[2x+1] = G(x-3), G(j)=g[j] for
// j in [0,10] else 0. Packed phase-1 taps read f2 pairs from adjacent SGPRs;
// scalar weight g[k] = gg[2*(k+2)]. Zero-padding makes tap masking branchless.
struct GaussP { float gg[32]; };

// R0-champion structure (128 thr, f2 ring+phase2 -> v_pk_fma_f32 everywhere) with:
// (a) phase-1 packed output-pairs (branchless, SGPR weight pairs)
// (b) per-plane barrier = lgkmcnt(0)+s_barrier only (no vmcnt drain; prefetch
//     latency spans the full next plane; correctness of this barrier proven R4)
// (c) no VGPR weight array (kernarg SGPR reads)
__global__ __launch_bounds__(128, 2)
void ssim3d_kernel(const float* __restrict__ img1,
                   const float* __restrict__ img2,
                   float* __restrict__ out, GaussP gp)
{
    __shared__ float tmpA[5 * STAT];   // double buffer via pointer swap
    __shared__ float tmpB[5 * STAT];
    __shared__ float wsum[2];

    const int tid = threadIdx.x;        // 128 threads = 2 waves
    // phase-2 mapping: 16 rows x 8 col-pairs
    const int xc = tid & 7;             // cols 2xc, 2xc+1
    const int ty = tid >> 3;            // 0..15
    // phase-1 mapping: 26 rows x 4 quads (104 active)
    const int p1r = tid >> 2;
    const int p1q = tid & 3;

    const int blk = blockIdx.x;
    const int bw = blk % 10;
    const int bh = (blk / 10) % 10;
    const int bd = (blk / 100) % NDCH;
    const int bb = blk / (100 * NDCH);

    const int oh0 = bh * TH, ow0 = bw * TW, od0 = bd * DCH;
    const float* base1 = img1 + (size_t)bb * DD * HH * WW;
    const float* base2 = img2 + (size_t)bb * DD * HH * WW;

    // static D-ring: slot s holds output q with q % 11 == s (f2 = 2 W-cols)
    f2 a1[KK], a2[KK], a11[KK], a22[KK], a12[KK];
#pragma unroll
    for (int i = 0; i < KK; ++i) { a1[i]=0.f; a2[i]=0.f; a11[i]=0.f; a22[i]=0.f; a12[i]=0.f; }

    f2 lsum = 0.f;

    // phase-1 per-thread constants
    const int gh = oh0 - RAD + p1r;
    const bool p1act = (p1r < HALO_H);
    const bool rowok = p1act && ((unsigned)gh < (unsigned)HH);
    const int gc0 = ow0 + 4 * p1q - 8;                    // first loaded col (16B aligned)
    const size_t rowoff = (size_t)((unsigned)gh < (unsigned)HH ? gh : 0) * WW;

    // prefetch registers for the next plane's 20 cols per thread
    f4 pa[5], pb[5];
#pragma unroll
    for (int j = 0; j < 5; ++j) { pa[j] = (f4)0.f; pb[j] = (f4)0.f; }

    float* twr = tmpA;   // buffer written (and read) this plane
    float* trd = tmpB;   // buffer of the previous plane

    // preamble: prefetch plane p=0 if valid
    {
        const int dn = od0 - RAD;
        if (p1act && (unsigned)dn < (unsigned)DD) {
            const size_t pbv = (size_t)dn * (HH * WW) + rowoff;
#pragma unroll
            for (int j = 0; j < 5; ++j) {
                const int gc = gc0 + 4 * j;
                f4 za = (f4)0.f, zb = (f4)0.f;
                if (rowok && gc >= 0 && gc <= WW - 4) {
                    za = *(const f4*)(base1 + pbv + gc);
                    zb = *(const f4*)(base2 + pbv + gc);
                }
                pa[j] = za; pb[j] = zb;
            }
        }
    }

    int pcbase = 0;
    auto body = [&](auto uc) {
        constexpr int U = decltype(uc)::value;
        const int p = pcbase + U;
        const int d = od0 - RAD + p;
        const bool dval = (p < NPLANES) && ((unsigned)d < (unsigned)DD);  // block-uniform

        // ---- phase 1: packed W-conv of 5 stats from prefetched regs ----
        if (dval && p1act) {
            // q0[st] = outputs (0,1), q1[st] = outputs (2,3); st: mu1,mu2,e11,e22,e12
            f2 q0[5], q1[5];
#pragma unroll
            for (int st = 0; st < 5; ++st) { q0[st] = 0.f; q1[st] = 0.f; }
#pragma unroll
            for (int j = 0; j < 5; ++j) {
#pragma unroll
                for (int ii = 0; ii < 4; ++ii) {
                    const int i = 4 * j + ii;          // local col 0..19; need 3..16
                    if (i < 3 || i > 16) continue;
                    const float av = pa[j][ii], bv = pb[j][ii];
                    const float aa = av * av, bb2 = bv * bv, ab = av * bv;
                    // pair (t0,t1): taps (i-3, i-4) -> gg[i-1]; pair (t2,t3): gg[i-3]
                    const f2 w01 = { gp.gg[2*(i-1)], gp.gg[2*(i-1)+1] };
                    const f2 w23 = { gp.gg[2*(i-3)], gp.gg[2*(i-3)+1] };
                    q0[0] += w01 * av;   q1[0] += w23 * av;
                    q0[1] += w01 * bv;   q1[1] += w23 * bv;
                    q0[2] += w01 * aa;   q1[2] += w23 * aa;
                    q0[3] += w01 * bb2;  q1[3] += w23 * bb2;
                    q0[4] += w01 * ab;   q1[4] += w23 * ab;
                }
            }
            float* tw = twr + p1r * TS + 4 * p1q;      // 16B-aligned
#pragma unroll
            for (int st = 0; st < 5; ++st) {
                f4 v;
                v[0] = q0[st][0]; v[1] = q0[st][1];
                v[2] = q1[st][0]; v[3] = q1[st][1];
                *(f4*)(tw + st * STAT) = v;
            }
        }

        // ---- prefetch plane p+1 (waitcnt lands at first use, next body) ----
        {
            const int pn = p + 1;
            const int dn = od0 - RAD + pn;
            if (p1act && (pn < NPLANES) && ((unsigned)dn < (unsigned)DD)) {
                const size_t pbv = (size_t)dn * (HH * WW) + rowoff;
#pragma unroll
                for (int j = 0; j < 5; ++j) {
                    const int gc = gc0 + 4 * j;
                    f4 za = (f4)0.f, zb = (f4)0.f;
                    if (rowok && gc >= 0 && gc <= WW - 4) {
                        za = *(const f4*)(base1 + pbv + gc);
                        zb = *(const f4*)(base2 + pbv + gc);
                    }
                    pa[j] = za; pb[j] = zb;
                }
            }
        }

        // ---- phase 2: H-conv (f2 b64, conflict-free) + static-slot D scatter ----
        if (dval) {
            // Raw barrier: order LDS tmp traffic only (lgkmcnt). Deliberately NO
            // vmcnt(0) drain -- prefetch loads complete behind the next plane.
            asm volatile("s_waitcnt lgkmcnt(0)\n\ts_barrier" ::: "memory");
            f2 P1 = 0.f, P2 = 0.f, P11 = 0.f, P22 = 0.f, P12 = 0.f;
            const float* tb = twr + (ty * TS + 2 * xc);
#pragma unroll
            for (int k = 0; k < KK; ++k) {
                const float w = gp.gg[2 * (k + 2)];    // scalar g[k] from SGPR
                const int o = k * TS;
                P1  += w * *(const f2*)(tb + 0*STAT + o);
                P2  += w * *(const f2*)(tb + 1*STAT + o);
                P11 += w * *(const f2*)(tb + 2*STAT + o);
                P22 += w * *(const f2*)(tb + 3*STAT + o);
                P12 += w * *(const f2*)(tb + 4*STAT + o);
            }
#pragma unroll
            for (int t = 0; t < KK; ++t) {
                constexpr int base = U + 22;
                const int s = (base - t) % 11;         // folds: U, t compile-time
                const float w = gp.gg[2 * (t + 2)];
                a1[s]  += w * P1;
                a2[s]  += w * P2;
                a11[s] += w * P11;
                a22[s] += w * P22;
                a12[s] += w * P12;
            }
        }

        // ---- emit output q = p-10 from fixed slot (U+1)%11, then zero it ----
        constexpr int e = (U + 1) % 11;
        if (p >= 2 * RAD && p < NPLANES) {
            f2 mu1 = a1[e], mu2 = a2[e];
            f2 m11 = mu1 * mu1, m22 = mu2 * mu2, m12 = mu1 * mu2;
            f2 sg1 = a11[e] - m11, sg2 = a22[e] - m22, sg12 = a12[e] - m12;
            const float C1c = 0.0001f, C2c = 0.0009f;
            f2 num = (2.f * m12 + C1c) * (2.f * sg12 + C2c);
            f2 den = (m11 + m22 + C1c) * (sg1 + sg2 + C2c);
            lsum += num / den;
        }
        a1[e] = 0.f; a2[e] = 0.f; a11[e] = 0.f; a22[e] = 0.f; a12[e] = 0.f;

        // swap double buffers
        float* t = twr; twr = trd; trd = t;
    };

    for (pcbase = 0; pcbase < 44; pcbase += 11) {
        body(std::integral_constant<int, 0>{});
        body(std::integral_constant<int, 1>{});
        body(std::integral_constant<int, 2>{});
        body(std::integral_constant<int, 3>{});
        body(std::integral_constant<int, 4>{});
        body(std::integral_constant<int, 5>{});
        body(std::integral_constant<int, 6>{});
        body(std::integral_constant<int, 7>{});
        body(std::integral_constant<int, 8>{});
        body(std::integral_constant<int, 9>{});
        body(std::integral_constant<int, 10>{});
    }

    // ---- reduction: wave shuffle -> LDS -> one atomic per block ----
    float v = lsum.x + lsum.y;
#pragma unroll
    for (int off = 32; off > 0; off >>= 1)
        v += __shfl_down(v, off, 64);
    if ((tid & 63) == 0) wsum[tid >> 6] = v;
    __syncthreads();
    if (tid == 0) {
        const float inv_n = 1.0f / ((float)BB * DD * HH * WW);
        atomicAdd(out, (wsum[0] + wsum[1]) * inv_n);
    }
}

extern "C" void kernel_launch(void* const* d_in, const int* in_sizes, int n_in,
                              void* d_out, int out_size, void* d_ws, size_t ws_size,
                              hipStream_t stream) {
    const float* img1 = (const float*)d_in[0];
    const float* img2 = (const float*)d_in[1];
    float* out = (float*)d_out;

    double gd[KK], sum = 0.0;
    for (int i = 0; i < KK; ++i) {
        double x = (double)(i - KK / 2);
        gd[i] = exp(-(x * x) / (2.0 * 1.5 * 1.5));
        sum += gd[i];
    }
    float gf[KK];
    for (int i = 0; i < KK; ++i) gf[i] = (float)(gd[i] / sum);

    GaussP gp;
    for (int x = 0; x < 16; ++x) {
        const int j0 = x - 2, j1 = x - 3;
        gp.gg[2 * x]     = (j0 >= 0 && j0 < KK) ? gf[j0] : 0.0f;
        gp.gg[2 * x + 1] = (j1 >= 0 && j1 < KK) ? gf[j1] : 0.0f;
    }

    hipMemsetAsync(d_out, 0, sizeof(float), stream);

    dim3 grid(10 * 10 * NDCH * BB);   // 2000 blocks
    dim3 block(128);
    hipLaunchKernelGGL(ssim3d_kernel, grid, block, 0, stream,
                       img1, img2, out, gp);
}